// Round 2
// baseline (523.756 us; speedup 1.0000x reference)
//
#include <hip/hip_runtime.h>
#include <stdint.h>

#define NNODES 100000
#define NEDGES 400000

typedef __attribute__((ext_vector_type(4))) float f32x4;
typedef __attribute__((ext_vector_type(8))) short bf16x8;

__device__ __forceinline__ short f2b(float x){
  union { float f; uint32_t u; } v; v.f = x;
  uint32_t r = v.u + 0x7FFFu + ((v.u >> 16) & 1u);
  return (short)(r >> 16);
}
__device__ __forceinline__ float b2f(short x){
  union { uint32_t u; float f; } v; v.u = ((uint32_t)(unsigned short)x) << 16; return v.f;
}
__device__ __forceinline__ bf16x8 pack_bf8(f32x4 a, f32x4 b){
  bf16x8 r;
  r[0]=f2b(a[0]); r[1]=f2b(a[1]); r[2]=f2b(a[2]); r[3]=f2b(a[3]);
  r[4]=f2b(b[0]); r[5]=f2b(b[1]); r[6]=f2b(b[2]); r[7]=f2b(b[3]);
  return r;
}

// Pack all 9 weight blocks (each 128x128) into B-frag tiles [kt][g][n][j]:
// dst[seg][kt*4096 + g*1024 + n*8 + j] = bf16(W[koff + kt*32+g*8+j][n])
// seg order: 0 eW1[0:128], 1 eW1[128:256], 2 nW1[0:128]   (consumed by compute_T)
//            3 eW1[256:384], 4 nW1[128:256], 5 eW2, 6 eW3, 7 nW2, 8 nW3
__global__ void pack_all(const float* __restrict__ eW1, const float* __restrict__ eW2,
                         const float* __restrict__ eW3, const float* __restrict__ nW1,
                         const float* __restrict__ nW2, const float* __restrict__ nW3,
                         short* __restrict__ dst){
  int o = blockIdx.x*256 + threadIdx.x;       // 0 .. 9*16384
  int seg = o >> 14, rem = o & 16383;
  int kt = rem >> 12, g = (rem >> 10) & 3, n = (rem >> 3) & 127, j = rem & 7;
  int k = kt*32 + g*8 + j;
  const float* src = eW1; int koff = 0;
  switch(seg){
    case 0: src=eW1; koff=0;   break;
    case 1: src=eW1; koff=128; break;
    case 2: src=nW1; koff=0;   break;
    case 3: src=eW1; koff=256; break;
    case 4: src=nW1; koff=128; break;
    case 5: src=eW2; break;
    case 6: src=eW3; break;
    case 7: src=nW2; break;
    case 8: src=nW3; break;
  }
  dst[o] = f2b(src[(size_t)(koff+k)*128 + n]);
}

// T[node][0:128]=nodes@W1s, [128:256]=nodes@W1r, [256:384]=nodes@nW1a  (bf16, no bias)
__global__ __launch_bounds__(512,4) void compute_T(
    const float* __restrict__ nodef, const short* __restrict__ wp,
    short* __restrict__ Tt, int nrows)
{
  __shared__ __align__(16) short Ws[16384];
  const int tid=threadIdx.x, lane=tid&63, wid=tid>>6, l16=lane&15, hi=lane>>4;
  const int row0 = blockIdx.x*128;
  const int arow_l = wid*16 + l16;
  const int arow_c = min(row0 + arow_l, nrows-1);
  const float* s = nodef + (size_t)arow_c*128;

  bf16x8 af[4];
  #pragma unroll
  for (int kt=0; kt<4; kt++){
    int ko = kt*32 + hi*8;
    af[kt] = pack_bf8(*(const f32x4*)(s+ko), *(const f32x4*)(s+ko+4));
  }
  int4 w[4];
  #pragma unroll
  for (int i=0;i<4;i++) w[i] = ((const int4*)wp)[tid + 512*i];

  for (int o=0; o<3; o++){
    if (o) __syncthreads();
    #pragma unroll
    for (int i=0;i<4;i++) ((int4*)Ws)[tid + 512*i] = w[i];
    if (o < 2){
      #pragma unroll
      for (int i=0;i<4;i++) w[i] = ((const int4*)(wp + (o+1)*16384))[tid + 512*i];
    }
    __syncthreads();
    f32x4 acc[8];
    #pragma unroll
    for (int t=0;t<8;t++) acc[t] = (f32x4)(0.0f);
    #pragma unroll
    for (int kt=0;kt<4;kt++){
      #pragma unroll
      for (int t=0;t<8;t++){
        bf16x8 bw = *(const bf16x8*)&Ws[kt*4096 + hi*1024 + (t*16+l16)*8];
        acc[t] = __builtin_amdgcn_mfma_f32_16x16x32_bf16(af[kt], bw, acc[t], 0,0,0);
      }
    }
    #pragma unroll
    for (int t=0;t<8;t++){
      int col = t*16 + l16;
      #pragma unroll
      for (int r=0;r<4;r++){
        int row = row0 + wid*16 + hi*4 + r;
        if (row < nrows) Tt[(size_t)row*384 + o*128 + col] = f2b(acc[t][r]);
      }
    }
  }
}

// MODE 0: edge MLP rows=edges. L1 = edges@W1e + G (G = T_s[snd]+T_r[rcv], LDS-staged) + b1
//         epilogue: out = LN+edge residual, atomicAdd LN -> agg[rcv]
// MODE 1: node MLP rows=nodes. L1 = agg@W1nb + T[row][256:384] + b1; out = LN+node residual
template<int MODE>
__global__ __launch_bounds__(512,4) void gnb_mlp(
    const float* __restrict__ nodef, const float* __restrict__ edgef,
    const int* __restrict__ snd, const int* __restrict__ rcv,
    const short* __restrict__ Tt,
    const short* __restrict__ Wp1, const short* __restrict__ Wp2, const short* __restrict__ Wp3,
    const float* __restrict__ b1p, const float* __restrict__ b2p, const float* __restrict__ b3p,
    const float* __restrict__ gmp, const float* __restrict__ btp,
    float* __restrict__ agg, float* __restrict__ outp, int nrows)
{
  __shared__ __align__(16) short Ws[16384];   // one 128x128 bf16 weight, [kt][g][n][j]
  __shared__ __align__(16) short HGs[16384];  // [128][128] bf16, XOR-swizzled; G then H

  const int tid=threadIdx.x, lane=tid&63, wid=tid>>6, l16=lane&15, hi=lane>>4;
  const int row0 = blockIdx.x*128;
  const int arow_l = wid*16 + l16;
  const int arow_c = min(row0 + arow_l, nrows-1);

  // issue W1 stage loads early
  int4 w[4];
  #pragma unroll
  for (int i=0;i<4;i++) w[i] = ((const int4*)Wp1)[tid + 512*i];

  // gather-stage G = T_s[snd] + T_r[rcv] into HGs (2048 16B-chunk tasks / 512 thr)
  if (MODE==0){
    #pragma unroll
    for (int u=0;u<4;u++){
      int q = tid + u*512;
      int gr = q >> 4, c = q & 15;              // local row 0..127, 16B chunk 0..15
      int grow = row0 + gr;                      // exact (NEDGES % 128 == 0)
      int si = snd[grow], ri = rcv[grow];
      bf16x8 a = *(const bf16x8*)(Tt + (size_t)si*384 + c*8);
      bf16x8 b = *(const bf16x8*)(Tt + (size_t)ri*384 + 128 + c*8);
      bf16x8 o8;
      #pragma unroll
      for (int j=0;j<8;j++) o8[j] = f2b(b2f(a[j]) + b2f(b[j]));
      *(bf16x8*)((char*)HGs + gr*256 + ((c*16) ^ ((gr&7)<<4))) = o8;
    }
  }
  #pragma unroll
  for (int i=0;i<4;i++) ((int4*)Ws)[tid + 512*i] = w[i];
  #pragma unroll
  for (int i=0;i<4;i++) w[i] = ((const int4*)Wp2)[tid + 512*i];   // preload W2
  __syncthreads();

  f32x4 acc[8];
  #pragma unroll
  for (int t=0;t<8;t++) acc[t] = (f32x4)(0.0f);

  // ---- layer 1: A = (edges | agg) row, coalesced from global ----
  const float* s1 = (MODE==0) ? (edgef + (size_t)arow_c*128) : (agg + (size_t)arow_c*128);
  #pragma unroll
  for (int kt=0;kt<4;kt++){
    int ko = kt*32 + hi*8;
    bf16x8 af = pack_bf8(*(const f32x4*)(s1+ko), *(const f32x4*)(s1+ko+4));
    #pragma unroll
    for (int t=0;t<8;t++){
      bf16x8 bw = *(const bf16x8*)&Ws[kt*4096 + hi*1024 + (t*16+l16)*8];
      acc[t] = __builtin_amdgcn_mfma_f32_16x16x32_bf16(af, bw, acc[t], 0,0,0);
    }
  }
  // epi 1: + G + b1, relu -> HGs (element-wise same-lane read-then-overwrite)
  #pragma unroll
  for (int t=0;t<8;t++){
    int col = t*16 + l16;
    float bb = b1p[col];
    #pragma unroll
    for (int r=0;r<4;r++){
      int row = wid*16 + hi*4 + r;
      float g;
      if (MODE==0){
        g = b2f(*(const short*)((char*)HGs + row*256 + ((col*2) ^ ((row&7)<<4))));
      } else {
        int grow = min(row0 + row, nrows-1);
        g = b2f(Tt[(size_t)grow*384 + 256 + col]);
      }
      float v = fmaxf(acc[t][r] + g + bb, 0.0f);
      *(short*)((char*)HGs + row*256 + ((col*2) ^ ((row&7)<<4))) = f2b(v);
      acc[t][r] = 0.0f;
    }
  }
  __syncthreads();
  #pragma unroll
  for (int i=0;i<4;i++) ((int4*)Ws)[tid + 512*i] = w[i];          // W2
  #pragma unroll
  for (int i=0;i<4;i++) w[i] = ((const int4*)Wp3)[tid + 512*i];   // preload W3
  __syncthreads();

  // ---- layer 2: A from HGs (wave-private rows) ----
  #pragma unroll
  for (int kt=0;kt<4;kt++){
    bf16x8 af = *(const bf16x8*)((char*)HGs + arow_l*256 + ((kt*64 + hi*16) ^ ((arow_l&7)<<4)));
    #pragma unroll
    for (int t=0;t<8;t++){
      bf16x8 bw = *(const bf16x8*)&Ws[kt*4096 + hi*1024 + (t*16+l16)*8];
      acc[t] = __builtin_amdgcn_mfma_f32_16x16x32_bf16(af, bw, acc[t], 0,0,0);
    }
  }
  #pragma unroll
  for (int t=0;t<8;t++){
    float bb = b2p[t*16+l16];
    int col2 = (t*16+l16)*2;
    #pragma unroll
    for (int r=0;r<4;r++){
      float v = fmaxf(acc[t][r] + bb, 0.0f);
      int row = wid*16 + hi*4 + r;
      *(short*)((char*)HGs + row*256 + (col2 ^ ((row&7)<<4))) = f2b(v);
      acc[t][r] = 0.0f;
    }
  }
  __syncthreads();
  #pragma unroll
  for (int i=0;i<4;i++) ((int4*)Ws)[tid + 512*i] = w[i];          // W3
  __syncthreads();

  // ---- layer 3 ----
  #pragma unroll
  for (int kt=0;kt<4;kt++){
    bf16x8 af = *(const bf16x8*)((char*)HGs + arow_l*256 + ((kt*64 + hi*16) ^ ((arow_l&7)<<4)));
    #pragma unroll
    for (int t=0;t<8;t++){
      bf16x8 bw = *(const bf16x8*)&Ws[kt*4096 + hi*1024 + (t*16+l16)*8];
      acc[t] = __builtin_amdgcn_mfma_f32_16x16x32_bf16(af, bw, acc[t], 0,0,0);
    }
  }

  // ---- LayerNorm (in-register) + epilogue ----
  float ps[4] = {0,0,0,0}, pq[4] = {0,0,0,0};
  #pragma unroll
  for (int t=0;t<8;t++){
    float bb = b3p[t*16+l16];
    #pragma unroll
    for (int r=0;r<4;r++){
      float v = acc[t][r] + bb;
      acc[t][r] = v;
      ps[r] += v; pq[r] += v*v;
    }
  }
  #pragma unroll
  for (int m=1;m<16;m<<=1){
    #pragma unroll
    for (int r=0;r<4;r++){
      ps[r] += __shfl_xor(ps[r], m);
      pq[r] += __shfl_xor(pq[r], m);
    }
  }
  float mu[4], rs[4];
  #pragma unroll
  for (int r=0;r<4;r++){
    mu[r] = ps[r] * (1.0f/128.0f);
    float var = pq[r] * (1.0f/128.0f) - mu[r]*mu[r];
    rs[r] = rsqrtf(var + 1e-5f);
  }

  int erow[4]; int rdst[4] = {0,0,0,0};
  #pragma unroll
  for (int r=0;r<4;r++){
    erow[r] = row0 + wid*16 + hi*4 + r;
    if (MODE==0) rdst[r] = rcv[erow[r]];
  }

  #pragma unroll
  for (int t=0;t<8;t++){
    int col = t*16 + l16;
    float gm = gmp[col], be = btp[col];
    #pragma unroll
    for (int r=0;r<4;r++){
      float y = (acc[t][r]-mu[r])*rs[r]*gm + be;
      if (MODE==0){
        size_t o = (size_t)erow[r]*128 + col;
        outp[o] = y + edgef[o];
        atomicAdd(agg + (size_t)rdst[r]*128 + col, y);
      } else {
        if (erow[r] < nrows){
          size_t o = (size_t)erow[r]*128 + col;
          outp[o] = y + nodef[o];
        }
      }
    }
  }
}

extern "C" void kernel_launch(void* const* d_in, const int* in_sizes, int n_in,
                              void* d_out, int out_size, void* d_ws, size_t ws_size,
                              hipStream_t stream)
{
  (void)in_sizes; (void)n_in; (void)out_size; (void)ws_size;
  const float* nodef = (const float*)d_in[0];
  const float* edgef = (const float*)d_in[1];
  const int*   snd   = (const int*)d_in[2];
  const int*   rcv   = (const int*)d_in[3];
  const float* eW1 = (const float*)d_in[4];
  const float* eb1 = (const float*)d_in[5];
  const float* eW2 = (const float*)d_in[6];
  const float* eb2 = (const float*)d_in[7];
  const float* eW3 = (const float*)d_in[8];
  const float* eb3 = (const float*)d_in[9];
  const float* egm = (const float*)d_in[10];
  const float* ebt = (const float*)d_in[11];
  const float* nW1 = (const float*)d_in[12];
  const float* nb1 = (const float*)d_in[13];
  const float* nW2 = (const float*)d_in[14];
  const float* nb2 = (const float*)d_in[15];
  const float* nW3 = (const float*)d_in[16];
  const float* nb3 = (const float*)d_in[17];
  const float* ngm = (const float*)d_in[18];
  const float* nbt = (const float*)d_in[19];

  float* agg = (float*)d_ws;                                              // 51.2 MB
  short* Tt  = (short*)((char*)d_ws + (size_t)NNODES*128*4);              // 76.8 MB
  short* wp  = (short*)((char*)d_ws + (size_t)NNODES*128*4
                                    + (size_t)NNODES*384*2);              // 288 KB

  hipMemsetAsync(agg, 0, (size_t)NNODES*128*4, stream);
  pack_all<<<576,256,0,stream>>>(eW1,eW2,eW3,nW1,nW2,nW3,wp);
  compute_T<<<(NNODES+127)/128,512,0,stream>>>(nodef, wp, Tt, NNODES);

  float* out_nodes = (float*)d_out;
  float* out_edges = out_nodes + (size_t)NNODES*128;

  gnb_mlp<0><<<NEDGES/128,512,0,stream>>>(nodef, edgef, snd, rcv, Tt,
      wp+3*16384, wp+5*16384, wp+6*16384, eb1,eb2,eb3, egm,ebt, agg, out_edges, NEDGES);
  gnb_mlp<1><<<(NNODES+127)/128,512,0,stream>>>(nodef, edgef, snd, rcv, Tt,
      wp+4*16384, wp+7*16384, wp+8*16384, nb1,nb2,nb3, ngm,nbt, agg, out_nodes, NNODES);
}